// Round 6
// baseline (1165.312 us; speedup 1.0000x reference)
//
#include <hip/hip_runtime.h>
#include <math.h>

#define BN_EPS 1e-5f

// ---- workspace layout (in floats) ----
constexpr int Y2_ELEMS = 256 * 36 * 436;          // y2 intermediate
constexpr int WST_OFF  = Y2_ELEMS;                // WsT [p=c*24+h][36]
constexpr int CST_OFF  = WST_OFF + 864 * 36;      // a1,o1,a2,o2,a3,o3 (36 each)
constexpr int WCP_OFF  = CST_OFF + 216;           // Wc padded [o2*36+o][16]
constexpr int F_OFF    = WCP_OFF + 36 * 36 * 16;  // f features 256x288

// ------------------------------------------------------------------
// k0: fold BN consts + transpose Ws + pad Wc
// ------------------------------------------------------------------
__global__ __launch_bounds__(256) void k0_prep(
    const float* __restrict__ Ws, const float* __restrict__ Wc,
    const float* __restrict__ bt, const float* __restrict__ g1,
    const float* __restrict__ b1, const float* __restrict__ m1,
    const float* __restrict__ v1,
    const float* __restrict__ bs, const float* __restrict__ g2,
    const float* __restrict__ b2, const float* __restrict__ m2,
    const float* __restrict__ v2,
    const float* __restrict__ bc, const float* __restrict__ g3,
    const float* __restrict__ b3, const float* __restrict__ m3,
    const float* __restrict__ v3,
    float* __restrict__ ws) {
  int idx = blockIdx.x * 256 + threadIdx.x;
  if (idx < 36 * 864) {
    int o = idx / 864, p = idx - o * 864;
    ws[WST_OFF + p * 36 + o] = Ws[idx];
  }
  if (idx < 36 * 36 * 16) {
    int row = idx >> 4, k = idx & 15;
    ws[WCP_OFF + idx] = (k < 15) ? Wc[row * 15 + k] : 0.f;
  }
  if (idx < 216) {
    int l = idx / 36, c = idx - l * 36;
    float g, b, m, v, bias;
    if (l < 2)      { g = g1[c]; b = b1[c]; m = m1[c]; v = v1[c]; bias = bt[c]; }
    else if (l < 4) { g = g2[c]; b = b2[c]; m = m2[c]; v = v2[c]; bias = bs[c]; }
    else            { g = g3[c]; b = b3[c]; m = m3[c]; v = v3[c]; bias = bc[c]; }
    float s   = g / sqrtf(v + BN_EPS);
    float off = (bias - m) * s + b;
    ws[CST_OFF + idx] = (l & 1) ? off : s;
  }
}

// ------------------------------------------------------------------
// k1: fused conv1(1x65)+BN/ELU+conv2(864-reduce)+BN/ELU -> y2
// grid (28 t-tiles, 256 samples), 512 threads, 2-half K-split
// ------------------------------------------------------------------
constexpr int XPITCH = 81;   // x row pitch (+1 pad)
constexpr int WTP    = 68;   // Wt row pitch (float4-aligned)
constexpr int Y1P    = 20;   // y1 row pitch (float4-aligned)

__global__ __launch_bounds__(512, 6) void k1_conv12(
    const float* __restrict__ x, const float* __restrict__ Wt,
    const float* __restrict__ ws_ro, float* __restrict__ y2g) {
  __shared__ float sx[24 * XPITCH];                 // 7776 B
  __shared__ float sWt[36 * WTP];                   // 9792 B
  __shared__ alignas(16) float sy1[432 * Y1P];      // 34560 B (spart aliases)
  __shared__ float sc[144];

  float* spart = sy1;   // 7*72*8 = 4032 floats, used only after final barrier

  const int tid = threadIdx.x;
  const int t0  = blockIdx.x * 16;
  const int b   = blockIdx.y;
  const float* WsT = ws_ro + WST_OFF;

  // ---- stage ----
  for (int i = tid; i < 24 * 80; i += 512) {
    int h = i / 80, col = i - h * 80;
    int gc = t0 + col;
    float v = 0.f;
    if (gc < 500) v = x[b * 24024 + h * 1001 + 501 + gc];
    sx[h * XPITCH + col] = v;
  }
  for (int i = tid; i < 36 * 65; i += 512) {
    int c = i / 65, k = i - c * 65;
    sWt[c * WTP + k] = Wt[i];
  }
  if (tid < 144) sc[tid] = ws_ro[CST_OFF + tid];
  __syncthreads();

  // conv2 thread mapping: part 0..6 x (o4 0..8, t2 0..7)
  const int part = tid / 72;
  const int rr   = tid - part * 72;
  const int o4   = rr >> 3;
  const int t2   = rr & 7;
  const int p0   = part * 124;
  const int p1   = (p0 + 124 < 864) ? p0 + 124 : 864;
  float acc2[8];
#pragma unroll
  for (int i = 0; i < 8; ++i) acc2[i] = 0.f;

#pragma unroll 1
  for (int half = 0; half < 2; ++half) {
    // ---- conv1 half: 432 pairs ----
    if (tid < 432) {
      const int c = half * 18 + tid / 24;
      const int h = tid % 24;
      const float* xrow = sx + h * XPITCH;
      const float* wrow = sWt + c * WTP;
      float win[32];
#pragma unroll
      for (int j = 0; j < 32; ++j) win[j] = xrow[j];
      float acc[16];
#pragma unroll
      for (int t = 0; t < 16; ++t) acc[t] = 0.f;
#pragma unroll
      for (int cc = 0; cc < 4; ++cc) {
#pragma unroll
        for (int kq = 0; kq < 4; ++kq) {
          const int kb = cc * 16 + kq * 4;
          float4 w4 = *reinterpret_cast<const float4*>(wrow + kb);
          float wv[4] = {w4.x, w4.y, w4.z, w4.w};
#pragma unroll
          for (int kk = 0; kk < 4; ++kk) {
            const int k = kb + kk;
            const float w = wv[kk];
#pragma unroll
            for (int t = 0; t < 16; ++t)
              acc[t] = fmaf(w, win[(k + t) & 31], acc[t]);
            if (k < 48) win[k & 31] = xrow[k + 32];
          }
        }
      }
      {
        const float w = wrow[64];
#pragma unroll
        for (int t = 0; t < 16; ++t)
          acc[t] = fmaf(w, win[(64 + t) & 31], acc[t]);
      }
      const float a1 = sc[c], o1 = sc[36 + c];
      float yo[16];
#pragma unroll
      for (int t = 0; t < 16; ++t) {
        float v = fmaf(acc[t], a1, o1);
        yo[t] = v > 0.f ? v : __expf(v) - 1.f;
      }
      float* yrow = sy1 + tid * Y1P;
#pragma unroll
      for (int q = 0; q < 4; ++q)
        *reinterpret_cast<float4*>(yrow + q * 4) =
            make_float4(yo[q * 4], yo[q * 4 + 1], yo[q * 4 + 2], yo[q * 4 + 3]);
    }
    __syncthreads();

    // ---- conv2 partial on this half ----
    if (tid < 504) {
      int lo = p0 - half * 432; if (lo < 0) lo = 0;
      int hi = p1 - half * 432; if (hi > 432) hi = 432;
      const float* wb = WsT + o4 * 4;
      const float* yb = sy1 + t2 * 2;
      for (int lp = lo; lp < hi; ++lp) {
        const int p = half * 432 + lp;
        float4 w  = *reinterpret_cast<const float4*>(wb + p * 36);
        float2 yv = *reinterpret_cast<const float2*>(yb + lp * Y1P);
        acc2[0] = fmaf(w.x, yv.x, acc2[0]);
        acc2[1] = fmaf(w.x, yv.y, acc2[1]);
        acc2[2] = fmaf(w.y, yv.x, acc2[2]);
        acc2[3] = fmaf(w.y, yv.y, acc2[3]);
        acc2[4] = fmaf(w.z, yv.x, acc2[4]);
        acc2[5] = fmaf(w.z, yv.y, acc2[5]);
        acc2[6] = fmaf(w.w, yv.x, acc2[6]);
        acc2[7] = fmaf(w.w, yv.y, acc2[7]);
      }
    }
    __syncthreads();
  }

  // ---- write partials (lane-major: conflict-free) ----
  if (tid < 504) {
    float* pb = spart + tid * 8;
    *reinterpret_cast<float4*>(pb)     = make_float4(acc2[0], acc2[1], acc2[2], acc2[3]);
    *reinterpret_cast<float4*>(pb + 4) = make_float4(acc2[4], acc2[5], acc2[6], acc2[7]);
  }
  __syncthreads();

  // ---- reduce 7 partials + BN2/ELU + store ----
  for (int u = tid; u < 576; u += 512) {
    const int o = u >> 4, t = u & 15;
    const int o4u = o >> 2, iu = o & 3, t2u = t >> 1, ju = t & 1;
    float s = 0.f;
#pragma unroll
    for (int pp = 0; pp < 7; ++pp)
      s += spart[(pp * 72 + o4u * 8 + t2u) * 8 + iu * 2 + ju];
    float v = fmaf(s, sc[72 + o], sc[108 + o]);
    v = v > 0.f ? v : __expf(v) - 1.f;
    const int gt = t0 + t;
    if (gt < 436) y2g[(b * 36 + o) * 436 + gt] = v;
  }
}

// ------------------------------------------------------------------
// k2a: pool3 + conv3(1x15) + BN/ELU + pool15 -> f (256x288)
// grid (256 samples, 4 segments), 320 threads
// ------------------------------------------------------------------
__global__ __launch_bounds__(320) void k2a_feat(
    const float* __restrict__ y2g, const float* __restrict__ ws_ro,
    float* __restrict__ fws) {
  __shared__ float sy2[36 * 136];
  __shared__ float sp[36 * 48 + 8];
  __shared__ float sy3[36 * 32];
  const int tid = threadIdx.x;
  const int b   = blockIdx.x;
  const int seg = blockIdx.y;
  const int y2base = seg * 90;

  for (int i = tid; i < 36 * 135; i += 320) {
    int o = i / 135, col = i - o * 135;
    sy2[o * 136 + col] = y2g[(b * 36 + o) * 436 + y2base + col];
  }
  __syncthreads();

  for (int i = tid; i < 36 * 45; i += 320) {
    int o = i / 45, u = i - o * 45;
    const float* rp = sy2 + o * 136 + u * 3;
    sp[o * 48 + u] = (rp[0] + rp[1] + rp[2]) * (1.f / 3.f);
  }
  for (int i = tid; i < 36 * 3; i += 320) {
    int o = i / 3;
    sp[o * 48 + 45 + (i % 3)] = 0.f;
  }
  __syncthreads();

  // conv3: 288 units = 36 o2 x 8 t3-blocks(4)
  if (tid < 288) {
    const int o2 = tid >> 3, tb = tid & 7;
    float accv[4] = {0.f, 0.f, 0.f, 0.f};
    const float* wbase = ws_ro + WCP_OFF + (o2 * 36) * 16;
    for (int o = 0; o < 36; ++o) {
      const float* pr = sp + o * 48 + tb * 4;
      float4 p0 = reinterpret_cast<const float4*>(pr)[0];
      float4 p1 = reinterpret_cast<const float4*>(pr)[1];
      float4 p2 = reinterpret_cast<const float4*>(pr)[2];
      float4 p3 = reinterpret_cast<const float4*>(pr)[3];
      float4 p4 = reinterpret_cast<const float4*>(pr)[4];
      float win[20] = {p0.x, p0.y, p0.z, p0.w, p1.x, p1.y, p1.z, p1.w,
                       p2.x, p2.y, p2.z, p2.w, p3.x, p3.y, p3.z, p3.w,
                       p4.x, p4.y, p4.z, p4.w};
      const float4* wr = reinterpret_cast<const float4*>(wbase + o * 16);
      float4 w0 = wr[0], w1 = wr[1], w2 = wr[2], w3 = wr[3];
      float w[15] = {w0.x, w0.y, w0.z, w0.w, w1.x, w1.y, w1.z, w1.w,
                     w2.x, w2.y, w2.z, w2.w, w3.x, w3.y, w3.z};
#pragma unroll
      for (int k = 0; k < 15; ++k)
#pragma unroll
        for (int t = 0; t < 4; ++t)
          accv[t] = fmaf(w[k], win[k + t], accv[t]);
    }
    const float a3 = ws_ro[CST_OFF + 144 + o2];
    const float o3c = ws_ro[CST_OFF + 180 + o2];
#pragma unroll
    for (int t = 0; t < 4; ++t) {
      const int t3 = tb * 4 + t;
      if (t3 < 30) {
        float v = fmaf(accv[t], a3, o3c);
        sy3[o2 * 32 + t3] = v > 0.f ? v : __expf(v) - 1.f;
      }
    }
  }
  __syncthreads();

  // pool15 -> f (72 outputs this segment)
  if (tid < 72) {
    const int o2 = tid >> 1, jl = tid & 1;
    const float* rp = sy3 + o2 * 32 + jl * 15;
    float s = 0.f;
#pragma unroll
    for (int k = 0; k < 15; ++k) s += rp[k];
    fws[b * 288 + o2 * 8 + seg * 2 + jl] = s * (1.f / 15.f);
  }
}

// ------------------------------------------------------------------
// k2b: FC 288x288 + residual + /501
// ------------------------------------------------------------------
__global__ __launch_bounds__(320) void k2b_fc(
    const float* __restrict__ fws, const float* __restrict__ Wf,
    const float* __restrict__ bfv, float* __restrict__ out) {
  __shared__ float sf[288];
  const int tid = threadIdx.x, b = blockIdx.x;
  if (tid < 288) sf[tid] = fws[b * 288 + tid];
  __syncthreads();
  if (tid < 288) {
    const int n = tid;
    float acc = bfv[n] + sf[n];
#pragma unroll 4
    for (int m = 0; m < 288; ++m) acc = fmaf(sf[m], Wf[m * 288 + n], acc);
    out[b * 288 + n] = acc * (1.f / 501.f);
  }
}

// ------------------------------------------------------------------
extern "C" void kernel_launch(void* const* d_in, const int* in_sizes, int n_in,
                              void* d_out, int out_size, void* d_ws, size_t ws_size,
                              hipStream_t stream) {
  const float* x  = (const float*)d_in[0];
  const float* Wt = (const float*)d_in[1];
  const float* bt = (const float*)d_in[2];
  const float* g1 = (const float*)d_in[3];
  const float* b1 = (const float*)d_in[4];
  const float* m1 = (const float*)d_in[5];
  const float* v1 = (const float*)d_in[6];
  const float* Ws = (const float*)d_in[7];
  const float* bs = (const float*)d_in[8];
  const float* g2 = (const float*)d_in[9];
  const float* b2 = (const float*)d_in[10];
  const float* m2 = (const float*)d_in[11];
  const float* v2 = (const float*)d_in[12];
  const float* Wc = (const float*)d_in[13];
  const float* bc = (const float*)d_in[14];
  const float* g3 = (const float*)d_in[15];
  const float* b3 = (const float*)d_in[16];
  const float* m3 = (const float*)d_in[17];
  const float* v3 = (const float*)d_in[18];
  const float* Wf = (const float*)d_in[19];
  const float* bf = (const float*)d_in[20];

  float* ws  = (float*)d_ws;
  float* out = (float*)d_out;

  k0_prep<<<dim3(122), dim3(256), 0, stream>>>(Ws, Wc, bt, g1, b1, m1, v1,
                                               bs, g2, b2, m2, v2,
                                               bc, g3, b3, m3, v3, ws);
  k1_conv12<<<dim3(28, 256), dim3(512), 0, stream>>>(x, Wt, ws, ws);
  k2a_feat<<<dim3(256, 4), dim3(320), 0, stream>>>(ws, ws, ws + F_OFF);
  k2b_fc<<<dim3(256), dim3(320), 0, stream>>>(ws + F_OFF, Wf, bf, out);
}

// Round 10
// 755.316 us; speedup vs baseline: 1.5428x; 1.5428x over previous
//
#include <hip/hip_runtime.h>
#include <math.h>

#define BN_EPS 1e-5f

// ---- workspace layout (in floats) ----
constexpr int Y2_ELEMS = 256 * 36 * 436;          // y2 intermediate
constexpr int WST_OFF  = Y2_ELEMS;                // WsT [p=c*24+h][36]
constexpr int CST_OFF  = WST_OFF + 864 * 36;      // a1,o1,a2,o2,a3,o3 (36 each)
constexpr int WCP_OFF  = CST_OFF + 216;           // Wc padded [o2*36+o][16]
constexpr int F_OFF    = WCP_OFF + 36 * 36 * 16;  // f features 256x288

// ------------------------------------------------------------------
// k0: fold BN consts + transpose Ws + pad Wc
// ------------------------------------------------------------------
__global__ __launch_bounds__(256) void k0_prep(
    const float* __restrict__ Ws, const float* __restrict__ Wc,
    const float* __restrict__ bt, const float* __restrict__ g1,
    const float* __restrict__ b1, const float* __restrict__ m1,
    const float* __restrict__ v1,
    const float* __restrict__ bs, const float* __restrict__ g2,
    const float* __restrict__ b2, const float* __restrict__ m2,
    const float* __restrict__ v2,
    const float* __restrict__ bc, const float* __restrict__ g3,
    const float* __restrict__ b3, const float* __restrict__ m3,
    const float* __restrict__ v3,
    float* __restrict__ ws) {
  int idx = blockIdx.x * 256 + threadIdx.x;
  if (idx < 36 * 864) {
    int o = idx / 864, p = idx - o * 864;
    ws[WST_OFF + p * 36 + o] = Ws[idx];
  }
  if (idx < 36 * 36 * 16) {
    int row = idx >> 4, k = idx & 15;
    ws[WCP_OFF + idx] = (k < 15) ? Wc[row * 15 + k] : 0.f;
  }
  if (idx < 216) {
    int l = idx / 36, c = idx - l * 36;
    float g, b, m, v, bias;
    if (l < 2)      { g = g1[c]; b = b1[c]; m = m1[c]; v = v1[c]; bias = bt[c]; }
    else if (l < 4) { g = g2[c]; b = b2[c]; m = m2[c]; v = v2[c]; bias = bs[c]; }
    else            { g = g3[c]; b = b3[c]; m = m3[c]; v = v3[c]; bias = bc[c]; }
    float s   = g / sqrtf(v + BN_EPS);
    float off = (bias - m) * s + b;
    ws[CST_OFF + idx] = (l & 1) ? off : s;
  }
}

// ------------------------------------------------------------------
// k1: fused conv1(1x65)+BN/ELU+conv2(864-reduce)+BN/ELU -> y2
// grid (28 t-tiles, 256 samples), 512 threads, 2-half K-split
// NOTE: plain __launch_bounds__(512). (512,6) clamped VGPR to 40 and
// spilled win[32]/acc[16] to scratch -> 1.9 GB HBM traffic, 1059 us.
// ------------------------------------------------------------------
constexpr int XPITCH = 81;   // x row pitch (+1 pad)
constexpr int WTP    = 68;   // Wt row pitch (float4-aligned)
constexpr int Y1P    = 20;   // y1 row pitch (float4-aligned)

__global__ __launch_bounds__(512) void k1_conv12(
    const float* __restrict__ x, const float* __restrict__ Wt,
    const float* __restrict__ ws_ro, float* __restrict__ y2g) {
  __shared__ float sx[24 * XPITCH];                 // 7776 B
  __shared__ float sWt[36 * WTP];                   // 9792 B
  __shared__ alignas(16) float sy1[432 * Y1P];      // 34560 B (spart aliases)
  __shared__ float sc[144];

  float* spart = sy1;   // 7*72*8 = 4032 floats, used only after final barrier

  const int tid = threadIdx.x;
  const int t0  = blockIdx.x * 16;
  const int b   = blockIdx.y;
  const float* WsT = ws_ro + WST_OFF;

  // ---- stage ----
  for (int i = tid; i < 24 * 80; i += 512) {
    int h = i / 80, col = i - h * 80;
    int gc = t0 + col;
    float v = 0.f;
    if (gc < 500) v = x[b * 24024 + h * 1001 + 501 + gc];
    sx[h * XPITCH + col] = v;
  }
  for (int i = tid; i < 36 * 65; i += 512) {
    int c = i / 65, k = i - c * 65;
    sWt[c * WTP + k] = Wt[i];
  }
  if (tid < 144) sc[tid] = ws_ro[CST_OFF + tid];
  __syncthreads();

  // conv2 thread mapping: part 0..6 x (o4 0..8, t2 0..7)
  const int part = tid / 72;
  const int rr   = tid - part * 72;
  const int o4   = rr >> 3;
  const int t2   = rr & 7;
  const int p0   = part * 124;
  const int p1   = (p0 + 124 < 864) ? p0 + 124 : 864;
  float acc2[8];
#pragma unroll
  for (int i = 0; i < 8; ++i) acc2[i] = 0.f;

#pragma unroll 1
  for (int half = 0; half < 2; ++half) {
    // ---- conv1 half: 432 pairs ----
    if (tid < 432) {
      const int c = half * 18 + tid / 24;
      const int h = tid % 24;
      const float* xrow = sx + h * XPITCH;
      const float* wrow = sWt + c * WTP;
      float win[32];
#pragma unroll
      for (int j = 0; j < 32; ++j) win[j] = xrow[j];
      float acc[16];
#pragma unroll
      for (int t = 0; t < 16; ++t) acc[t] = 0.f;
#pragma unroll
      for (int cc = 0; cc < 4; ++cc) {
#pragma unroll
        for (int kq = 0; kq < 4; ++kq) {
          const int kb = cc * 16 + kq * 4;
          float4 w4 = *reinterpret_cast<const float4*>(wrow + kb);
          float wv[4] = {w4.x, w4.y, w4.z, w4.w};
#pragma unroll
          for (int kk = 0; kk < 4; ++kk) {
            const int k = kb + kk;
            const float w = wv[kk];
#pragma unroll
            for (int t = 0; t < 16; ++t)
              acc[t] = fmaf(w, win[(k + t) & 31], acc[t]);
            if (k < 48) win[k & 31] = xrow[k + 32];
          }
        }
      }
      {
        const float w = wrow[64];
#pragma unroll
        for (int t = 0; t < 16; ++t)
          acc[t] = fmaf(w, win[(64 + t) & 31], acc[t]);
      }
      const float a1 = sc[c], o1 = sc[36 + c];
      float yo[16];
#pragma unroll
      for (int t = 0; t < 16; ++t) {
        float v = fmaf(acc[t], a1, o1);
        yo[t] = v > 0.f ? v : __expf(v) - 1.f;
      }
      float* yrow = sy1 + tid * Y1P;
#pragma unroll
      for (int q = 0; q < 4; ++q)
        *reinterpret_cast<float4*>(yrow + q * 4) =
            make_float4(yo[q * 4], yo[q * 4 + 1], yo[q * 4 + 2], yo[q * 4 + 3]);
    }
    __syncthreads();

    // ---- conv2 partial on this half ----
    if (tid < 504) {
      int lo = p0 - half * 432; if (lo < 0) lo = 0;
      int hi = p1 - half * 432; if (hi > 432) hi = 432;
      const float* wb = WsT + o4 * 4;
      const float* yb = sy1 + t2 * 2;
      for (int lp = lo; lp < hi; ++lp) {
        const int p = half * 432 + lp;
        float4 w  = *reinterpret_cast<const float4*>(wb + p * 36);
        float2 yv = *reinterpret_cast<const float2*>(yb + lp * Y1P);
        acc2[0] = fmaf(w.x, yv.x, acc2[0]);
        acc2[1] = fmaf(w.x, yv.y, acc2[1]);
        acc2[2] = fmaf(w.y, yv.x, acc2[2]);
        acc2[3] = fmaf(w.y, yv.y, acc2[3]);
        acc2[4] = fmaf(w.z, yv.x, acc2[4]);
        acc2[5] = fmaf(w.z, yv.y, acc2[5]);
        acc2[6] = fmaf(w.w, yv.x, acc2[6]);
        acc2[7] = fmaf(w.w, yv.y, acc2[7]);
      }
    }
    __syncthreads();
  }

  // ---- write partials (lane-major: conflict-free) ----
  if (tid < 504) {
    float* pb = spart + tid * 8;
    *reinterpret_cast<float4*>(pb)     = make_float4(acc2[0], acc2[1], acc2[2], acc2[3]);
    *reinterpret_cast<float4*>(pb + 4) = make_float4(acc2[4], acc2[5], acc2[6], acc2[7]);
  }
  __syncthreads();

  // ---- reduce 7 partials + BN2/ELU + store ----
  for (int u = tid; u < 576; u += 512) {
    const int o = u >> 4, t = u & 15;
    const int o4u = o >> 2, iu = o & 3, t2u = t >> 1, ju = t & 1;
    float s = 0.f;
#pragma unroll
    for (int pp = 0; pp < 7; ++pp)
      s += spart[(pp * 72 + o4u * 8 + t2u) * 8 + iu * 2 + ju];
    float v = fmaf(s, sc[72 + o], sc[108 + o]);
    v = v > 0.f ? v : __expf(v) - 1.f;
    const int gt = t0 + t;
    if (gt < 436) y2g[(b * 36 + o) * 436 + gt] = v;
  }
}

// ------------------------------------------------------------------
// k2a: pool3 + conv3(1x15) + BN/ELU + pool15 -> f (256x288)
// grid (256 samples, 4 segments), 320 threads
// ------------------------------------------------------------------
__global__ __launch_bounds__(320) void k2a_feat(
    const float* __restrict__ y2g, const float* __restrict__ ws_ro,
    float* __restrict__ fws) {
  __shared__ float sy2[36 * 136];
  __shared__ float sp[36 * 48 + 8];
  __shared__ float sy3[36 * 32];
  const int tid = threadIdx.x;
  const int b   = blockIdx.x;
  const int seg = blockIdx.y;
  const int y2base = seg * 90;

  for (int i = tid; i < 36 * 135; i += 320) {
    int o = i / 135, col = i - o * 135;
    sy2[o * 136 + col] = y2g[(b * 36 + o) * 436 + y2base + col];
  }
  __syncthreads();

  for (int i = tid; i < 36 * 45; i += 320) {
    int o = i / 45, u = i - o * 45;
    const float* rp = sy2 + o * 136 + u * 3;
    sp[o * 48 + u] = (rp[0] + rp[1] + rp[2]) * (1.f / 3.f);
  }
  for (int i = tid; i < 36 * 3; i += 320) {
    int o = i / 3;
    sp[o * 48 + 45 + (i % 3)] = 0.f;
  }
  __syncthreads();

  // conv3: 288 units = 36 o2 x 8 t3-blocks(4)
  if (tid < 288) {
    const int o2 = tid >> 3, tb = tid & 7;
    float accv[4] = {0.f, 0.f, 0.f, 0.f};
    const float* wbase = ws_ro + WCP_OFF + (o2 * 36) * 16;
    for (int o = 0; o < 36; ++o) {
      const float* pr = sp + o * 48 + tb * 4;
      float4 p0 = reinterpret_cast<const float4*>(pr)[0];
      float4 p1 = reinterpret_cast<const float4*>(pr)[1];
      float4 p2 = reinterpret_cast<const float4*>(pr)[2];
      float4 p3 = reinterpret_cast<const float4*>(pr)[3];
      float4 p4 = reinterpret_cast<const float4*>(pr)[4];
      float win[20] = {p0.x, p0.y, p0.z, p0.w, p1.x, p1.y, p1.z, p1.w,
                       p2.x, p2.y, p2.z, p2.w, p3.x, p3.y, p3.z, p3.w,
                       p4.x, p4.y, p4.z, p4.w};
      const float4* wr = reinterpret_cast<const float4*>(wbase + o * 16);
      float4 w0 = wr[0], w1 = wr[1], w2 = wr[2], w3 = wr[3];
      float w[15] = {w0.x, w0.y, w0.z, w0.w, w1.x, w1.y, w1.z, w1.w,
                     w2.x, w2.y, w2.z, w2.w, w3.x, w3.y, w3.z};
#pragma unroll
      for (int k = 0; k < 15; ++k)
#pragma unroll
        for (int t = 0; t < 4; ++t)
          accv[t] = fmaf(w[k], win[k + t], accv[t]);
    }
    const float a3 = ws_ro[CST_OFF + 144 + o2];
    const float o3c = ws_ro[CST_OFF + 180 + o2];
#pragma unroll
    for (int t = 0; t < 4; ++t) {
      const int t3 = tb * 4 + t;
      if (t3 < 30) {
        float v = fmaf(accv[t], a3, o3c);
        sy3[o2 * 32 + t3] = v > 0.f ? v : __expf(v) - 1.f;
      }
    }
  }
  __syncthreads();

  // pool15 -> f (72 outputs this segment)
  if (tid < 72) {
    const int o2 = tid >> 1, jl = tid & 1;
    const float* rp = sy3 + o2 * 32 + jl * 15;
    float s = 0.f;
#pragma unroll
    for (int k = 0; k < 15; ++k) s += rp[k];
    fws[b * 288 + o2 * 8 + seg * 2 + jl] = s * (1.f / 15.f);
  }
}

// ------------------------------------------------------------------
// k2b: FC 288x288 + residual + /501
// ------------------------------------------------------------------
__global__ __launch_bounds__(320) void k2b_fc(
    const float* __restrict__ fws, const float* __restrict__ Wf,
    const float* __restrict__ bfv, float* __restrict__ out) {
  __shared__ float sf[288];
  const int tid = threadIdx.x, b = blockIdx.x;
  if (tid < 288) sf[tid] = fws[b * 288 + tid];
  __syncthreads();
  if (tid < 288) {
    const int n = tid;
    float acc = bfv[n] + sf[n];
#pragma unroll 4
    for (int m = 0; m < 288; ++m) acc = fmaf(sf[m], Wf[m * 288 + n], acc);
    out[b * 288 + n] = acc * (1.f / 501.f);
  }
}

// ------------------------------------------------------------------
extern "C" void kernel_launch(void* const* d_in, const int* in_sizes, int n_in,
                              void* d_out, int out_size, void* d_ws, size_t ws_size,
                              hipStream_t stream) {
  const float* x  = (const float*)d_in[0];
  const float* Wt = (const float*)d_in[1];
  const float* bt = (const float*)d_in[2];
  const float* g1 = (const float*)d_in[3];
  const float* b1 = (const float*)d_in[4];
  const float* m1 = (const float*)d_in[5];
  const float* v1 = (const float*)d_in[6];
  const float* Ws = (const float*)d_in[7];
  const float* bs = (const float*)d_in[8];
  const float* g2 = (const float*)d_in[9];
  const float* b2 = (const float*)d_in[10];
  const float* m2 = (const float*)d_in[11];
  const float* v2 = (const float*)d_in[12];
  const float* Wc = (const float*)d_in[13];
  const float* bc = (const float*)d_in[14];
  const float* g3 = (const float*)d_in[15];
  const float* b3 = (const float*)d_in[16];
  const float* m3 = (const float*)d_in[17];
  const float* v3 = (const float*)d_in[18];
  const float* Wf = (const float*)d_in[19];
  const float* bf = (const float*)d_in[20];

  float* ws  = (float*)d_ws;
  float* out = (float*)d_out;

  k0_prep<<<dim3(122), dim3(256), 0, stream>>>(Ws, Wc, bt, g1, b1, m1, v1,
                                               bs, g2, b2, m2, v2,
                                               bc, g3, b3, m3, v3, ws);
  k1_conv12<<<dim3(28, 256), dim3(512), 0, stream>>>(x, Wt, ws, ws);
  k2a_feat<<<dim3(256, 4), dim3(320), 0, stream>>>(ws, ws, ws + F_OFF);
  k2b_fc<<<dim3(256), dim3(320), 0, stream>>>(ws + F_OFF, Wf, bf, out);
}

// Round 11
// 468.318 us; speedup vs baseline: 2.4883x; 1.6128x over previous
//
#include <hip/hip_runtime.h>
#include <math.h>

#define BN_EPS 1e-5f

// ---- workspace layout (in floats) ----
constexpr int Y2_ELEMS = 256 * 36 * 436;          // y2 intermediate
constexpr int WST_OFF  = Y2_ELEMS;                // WsTp [r=0..867][36] (padded: rows 432-433, 866-867 zero)
constexpr int WST_ROWS = 868;                     // 14 parts x 62 rows (2 halves x 434)
constexpr int CST_OFF  = WST_OFF + WST_ROWS * 36; // a1,o1,a2,o2,a3,o3 (36 each)
constexpr int WCP_OFF  = CST_OFF + 216;           // Wc padded [o2*36+o][16]
constexpr int F_OFF    = WCP_OFF + 36 * 36 * 16;  // f features 256x288

// ------------------------------------------------------------------
// k0: fold BN consts + build padded-transposed Ws + pad Wc
// ------------------------------------------------------------------
__global__ __launch_bounds__(256) void k0_prep(
    const float* __restrict__ Ws, const float* __restrict__ Wc,
    const float* __restrict__ bt, const float* __restrict__ g1,
    const float* __restrict__ b1, const float* __restrict__ m1,
    const float* __restrict__ v1,
    const float* __restrict__ bs, const float* __restrict__ g2,
    const float* __restrict__ b2, const float* __restrict__ m2,
    const float* __restrict__ v2,
    const float* __restrict__ bc, const float* __restrict__ g3,
    const float* __restrict__ b3, const float* __restrict__ m3,
    const float* __restrict__ v3,
    float* __restrict__ ws) {
  int idx = blockIdx.x * 256 + threadIdx.x;
  if (idx < WST_ROWS * 36) {
    int r = idx / 36, o = idx - r * 36;
    int half = (r >= 434) ? 1 : 0;
    int lp = r - half * 434;
    float val = 0.f;
    if (lp < 432) val = Ws[o * 864 + half * 432 + lp];   // pair p = c*24+h
    ws[WST_OFF + idx] = val;
  }
  if (idx < 36 * 36 * 16) {
    int row = idx >> 4, k = idx & 15;
    ws[WCP_OFF + idx] = (k < 15) ? Wc[row * 15 + k] : 0.f;
  }
  if (idx < 216) {
    int l = idx / 36, c = idx - l * 36;
    float g, b, m, v, bias;
    if (l < 2)      { g = g1[c]; b = b1[c]; m = m1[c]; v = v1[c]; bias = bt[c]; }
    else if (l < 4) { g = g2[c]; b = b2[c]; m = m2[c]; v = v2[c]; bias = bs[c]; }
    else            { g = g3[c]; b = b3[c]; m = m3[c]; v = v3[c]; bias = bc[c]; }
    float s   = g / sqrtf(v + BN_EPS);
    float off = (bias - m) * s + b;
    ws[CST_OFF + idx] = (l & 1) ? off : s;
  }
}

// ------------------------------------------------------------------
// k1: fused conv1(1x65)+BN/ELU+conv2(864-reduce)+BN/ELU -> y2
// grid (28 t-tiles, 256 samples), 512 threads, 2-half K-split.
// conv2 mapping: thread=(part 0..13, o 0..35), 1 scalar w load per
// 16 FMA, each WsTp element loaded exactly once per block (R10: the
// old 8-way-redundant float4 w stream was 7.2 GB of L2 traffic).
// ------------------------------------------------------------------
constexpr int XPITCH = 81;   // x row pitch (+1 pad)
constexpr int WTP    = 68;   // Wt row pitch (float4-aligned)
constexpr int Y1P    = 20;   // y1 row pitch (float4-aligned)

__global__ __launch_bounds__(512) void k1_conv12(
    const float* __restrict__ x, const float* __restrict__ Wt,
    const float* __restrict__ ws_ro, float* __restrict__ y2g) {
  __shared__ float sx[24 * XPITCH];                 // 7776 B
  __shared__ float sWt[36 * WTP];                   // 9792 B
  __shared__ alignas(16) float sy1[434 * Y1P];      // 34720 B (spart aliases)
  __shared__ float sc[144];

  float* spart = sy1;   // 14*36*16 = 8064 floats, used only after final barrier

  const int tid = threadIdx.x;
  const int t0  = blockIdx.x * 16;
  const int b   = blockIdx.y;
  const float* WsTp = ws_ro + WST_OFF;

  // ---- stage ----
  for (int i = tid; i < 24 * 80; i += 512) {
    int h = i / 80, col = i - h * 80;
    int gc = t0 + col;
    float v = 0.f;
    if (gc < 500) v = x[b * 24024 + h * 1001 + 501 + gc];
    sx[h * XPITCH + col] = v;
  }
  for (int i = tid; i < 36 * 65; i += 512) {
    int c = i / 65, k = i - c * 65;
    sWt[c * WTP + k] = Wt[i];
  }
  if (tid < 144) sc[tid] = ws_ro[CST_OFF + tid];
  if (tid >= 472) sy1[432 * Y1P + (tid - 472)] = 0.f;   // zero pad rows 432-433
  __syncthreads();

  // conv2 thread mapping: part 0..13 x o 0..35; per half 31 rows/part
  const int part = tid / 36;          // valid for tid < 504
  const int oo   = tid - part * 36;
  float acc2[16];
#pragma unroll
  for (int i = 0; i < 16; ++i) acc2[i] = 0.f;

#pragma unroll 1
  for (int half = 0; half < 2; ++half) {
    // ---- conv1 half: 432 pairs ----
    if (tid < 432) {
      const int c = half * 18 + tid / 24;
      const int h = tid % 24;
      const float* xrow = sx + h * XPITCH;
      const float* wrow = sWt + c * WTP;
      float win[32];
#pragma unroll
      for (int j = 0; j < 32; ++j) win[j] = xrow[j];
      float acc[16];
#pragma unroll
      for (int t = 0; t < 16; ++t) acc[t] = 0.f;
#pragma unroll
      for (int cc = 0; cc < 4; ++cc) {
#pragma unroll
        for (int kq = 0; kq < 4; ++kq) {
          const int kb = cc * 16 + kq * 4;
          float4 w4 = *reinterpret_cast<const float4*>(wrow + kb);
          float wv[4] = {w4.x, w4.y, w4.z, w4.w};
#pragma unroll
          for (int kk = 0; kk < 4; ++kk) {
            const int k = kb + kk;
            const float w = wv[kk];
#pragma unroll
            for (int t = 0; t < 16; ++t)
              acc[t] = fmaf(w, win[(k + t) & 31], acc[t]);
            if (k < 48) win[k & 31] = xrow[k + 32];
          }
        }
      }
      {
        const float w = wrow[64];
#pragma unroll
        for (int t = 0; t < 16; ++t)
          acc[t] = fmaf(w, win[(64 + t) & 31], acc[t]);
      }
      const float a1 = sc[c], o1 = sc[36 + c];
      float yo[16];
#pragma unroll
      for (int t = 0; t < 16; ++t) {
        float v = fmaf(acc[t], a1, o1);
        yo[t] = v > 0.f ? v : __expf(v) - 1.f;
      }
      float* yrow = sy1 + tid * Y1P;
#pragma unroll
      for (int q = 0; q < 4; ++q)
        *reinterpret_cast<float4*>(yrow + q * 4) =
            make_float4(yo[q * 4], yo[q * 4 + 1], yo[q * 4 + 2], yo[q * 4 + 3]);
    }
    __syncthreads();

    // ---- conv2 partial on this half: 31 rows, scalar w, 16 FMA/row ----
    if (tid < 504) {
      const float* wcol = WsTp + (half * 434 + part * 31) * 36 + oo;
      const float* yb   = sy1 + (part * 31) * Y1P;
#pragma unroll 4
      for (int i = 0; i < 31; ++i) {
        const float w = wcol[i * 36];
        const float4 ya = *reinterpret_cast<const float4*>(yb + i * Y1P);
        const float4 yc = *reinterpret_cast<const float4*>(yb + i * Y1P + 4);
        const float4 yd = *reinterpret_cast<const float4*>(yb + i * Y1P + 8);
        const float4 ye = *reinterpret_cast<const float4*>(yb + i * Y1P + 12);
        acc2[0]  = fmaf(w, ya.x, acc2[0]);
        acc2[1]  = fmaf(w, ya.y, acc2[1]);
        acc2[2]  = fmaf(w, ya.z, acc2[2]);
        acc2[3]  = fmaf(w, ya.w, acc2[3]);
        acc2[4]  = fmaf(w, yc.x, acc2[4]);
        acc2[5]  = fmaf(w, yc.y, acc2[5]);
        acc2[6]  = fmaf(w, yc.z, acc2[6]);
        acc2[7]  = fmaf(w, yc.w, acc2[7]);
        acc2[8]  = fmaf(w, yd.x, acc2[8]);
        acc2[9]  = fmaf(w, yd.y, acc2[9]);
        acc2[10] = fmaf(w, yd.z, acc2[10]);
        acc2[11] = fmaf(w, yd.w, acc2[11]);
        acc2[12] = fmaf(w, ye.x, acc2[12]);
        acc2[13] = fmaf(w, ye.y, acc2[13]);
        acc2[14] = fmaf(w, ye.z, acc2[14]);
        acc2[15] = fmaf(w, ye.w, acc2[15]);
      }
    }
    __syncthreads();
  }

  // ---- write partials (thread-major: conflict-free) ----
  if (tid < 504) {
    float* pb = spart + tid * 16;
#pragma unroll
    for (int q = 0; q < 4; ++q)
      *reinterpret_cast<float4*>(pb + q * 4) =
          make_float4(acc2[q * 4], acc2[q * 4 + 1], acc2[q * 4 + 2], acc2[q * 4 + 3]);
  }
  __syncthreads();

  // ---- reduce 14 partials + BN2/ELU + store ----
  for (int u = tid; u < 576; u += 512) {
    const int o = u >> 4, t = u & 15;
    float s = 0.f;
#pragma unroll
    for (int pp = 0; pp < 14; ++pp)
      s += spart[pp * 576 + u];
    float v = fmaf(s, sc[72 + o], sc[108 + o]);
    v = v > 0.f ? v : __expf(v) - 1.f;
    const int gt = t0 + t;
    if (gt < 436) y2g[(b * 36 + o) * 436 + gt] = v;
  }
}

// ------------------------------------------------------------------
// k2a: pool3 + conv3(1x15) + BN/ELU + pool15 -> f (256x288)
// grid (256 samples, 4 segments), 320 threads
// ------------------------------------------------------------------
__global__ __launch_bounds__(320) void k2a_feat(
    const float* __restrict__ y2g, const float* __restrict__ ws_ro,
    float* __restrict__ fws) {
  __shared__ float sy2[36 * 136];
  __shared__ float sp[36 * 48 + 8];
  __shared__ float sy3[36 * 32];
  const int tid = threadIdx.x;
  const int b   = blockIdx.x;
  const int seg = blockIdx.y;
  const int y2base = seg * 90;

  for (int i = tid; i < 36 * 135; i += 320) {
    int o = i / 135, col = i - o * 135;
    sy2[o * 136 + col] = y2g[(b * 36 + o) * 436 + y2base + col];
  }
  __syncthreads();

  for (int i = tid; i < 36 * 45; i += 320) {
    int o = i / 45, u = i - o * 45;
    const float* rp = sy2 + o * 136 + u * 3;
    sp[o * 48 + u] = (rp[0] + rp[1] + rp[2]) * (1.f / 3.f);
  }
  for (int i = tid; i < 36 * 3; i += 320) {
    int o = i / 3;
    sp[o * 48 + 45 + (i % 3)] = 0.f;
  }
  __syncthreads();

  // conv3: 288 units = 36 o2 x 8 t3-blocks(4)
  if (tid < 288) {
    const int o2 = tid >> 3, tb = tid & 7;
    float accv[4] = {0.f, 0.f, 0.f, 0.f};
    const float* wbase = ws_ro + WCP_OFF + (o2 * 36) * 16;
    for (int o = 0; o < 36; ++o) {
      const float* pr = sp + o * 48 + tb * 4;
      float4 p0 = reinterpret_cast<const float4*>(pr)[0];
      float4 p1 = reinterpret_cast<const float4*>(pr)[1];
      float4 p2 = reinterpret_cast<const float4*>(pr)[2];
      float4 p3 = reinterpret_cast<const float4*>(pr)[3];
      float4 p4 = reinterpret_cast<const float4*>(pr)[4];
      float win[20] = {p0.x, p0.y, p0.z, p0.w, p1.x, p1.y, p1.z, p1.w,
                       p2.x, p2.y, p2.z, p2.w, p3.x, p3.y, p3.z, p3.w,
                       p4.x, p4.y, p4.z, p4.w};
      const float4* wr = reinterpret_cast<const float4*>(wbase + o * 16);
      float4 w0 = wr[0], w1 = wr[1], w2 = wr[2], w3 = wr[3];
      float w[15] = {w0.x, w0.y, w0.z, w0.w, w1.x, w1.y, w1.z, w1.w,
                     w2.x, w2.y, w2.z, w2.w, w3.x, w3.y, w3.z};
#pragma unroll
      for (int k = 0; k < 15; ++k)
#pragma unroll
        for (int t = 0; t < 4; ++t)
          accv[t] = fmaf(w[k], win[k + t], accv[t]);
    }
    const float a3 = ws_ro[CST_OFF + 144 + o2];
    const float o3c = ws_ro[CST_OFF + 180 + o2];
#pragma unroll
    for (int t = 0; t < 4; ++t) {
      const int t3 = tb * 4 + t;
      if (t3 < 30) {
        float v = fmaf(accv[t], a3, o3c);
        sy3[o2 * 32 + t3] = v > 0.f ? v : __expf(v) - 1.f;
      }
    }
  }
  __syncthreads();

  // pool15 -> f (72 outputs this segment)
  if (tid < 72) {
    const int o2 = tid >> 1, jl = tid & 1;
    const float* rp = sy3 + o2 * 32 + jl * 15;
    float s = 0.f;
#pragma unroll
    for (int k = 0; k < 15; ++k) s += rp[k];
    fws[b * 288 + o2 * 8 + seg * 2 + jl] = s * (1.f / 15.f);
  }
}

// ------------------------------------------------------------------
// k2b: FC 288x288 + residual + /501
// ------------------------------------------------------------------
__global__ __launch_bounds__(320) void k2b_fc(
    const float* __restrict__ fws, const float* __restrict__ Wf,
    const float* __restrict__ bfv, float* __restrict__ out) {
  __shared__ float sf[288];
  const int tid = threadIdx.x, b = blockIdx.x;
  if (tid < 288) sf[tid] = fws[b * 288 + tid];
  __syncthreads();
  if (tid < 288) {
    const int n = tid;
    float acc = bfv[n] + sf[n];
#pragma unroll 4
    for (int m = 0; m < 288; ++m) acc = fmaf(sf[m], Wf[m * 288 + n], acc);
    out[b * 288 + n] = acc * (1.f / 501.f);
  }
}

// ------------------------------------------------------------------
extern "C" void kernel_launch(void* const* d_in, const int* in_sizes, int n_in,
                              void* d_out, int out_size, void* d_ws, size_t ws_size,
                              hipStream_t stream) {
  const float* x  = (const float*)d_in[0];
  const float* Wt = (const float*)d_in[1];
  const float* bt = (const float*)d_in[2];
  const float* g1 = (const float*)d_in[3];
  const float* b1 = (const float*)d_in[4];
  const float* m1 = (const float*)d_in[5];
  const float* v1 = (const float*)d_in[6];
  const float* Ws = (const float*)d_in[7];
  const float* bs = (const float*)d_in[8];
  const float* g2 = (const float*)d_in[9];
  const float* b2 = (const float*)d_in[10];
  const float* m2 = (const float*)d_in[11];
  const float* v2 = (const float*)d_in[12];
  const float* Wc = (const float*)d_in[13];
  const float* bc = (const float*)d_in[14];
  const float* g3 = (const float*)d_in[15];
  const float* b3 = (const float*)d_in[16];
  const float* m3 = (const float*)d_in[17];
  const float* v3 = (const float*)d_in[18];
  const float* Wf = (const float*)d_in[19];
  const float* bf = (const float*)d_in[20];

  float* ws  = (float*)d_ws;
  float* out = (float*)d_out;

  k0_prep<<<dim3(123), dim3(256), 0, stream>>>(Ws, Wc, bt, g1, b1, m1, v1,
                                               bs, g2, b2, m2, v2,
                                               bc, g3, b3, m3, v3, ws);
  k1_conv12<<<dim3(28, 256), dim3(512), 0, stream>>>(x, Wt, ws, ws);
  k2a_feat<<<dim3(256, 4), dim3(320), 0, stream>>>(ws, ws, ws + F_OFF);
  k2b_fc<<<dim3(256), dim3(320), 0, stream>>>(ws + F_OFF, Wf, bf, out);
}

// Round 12
// 384.272 us; speedup vs baseline: 3.0325x; 1.2187x over previous
//
#include <hip/hip_runtime.h>
#include <math.h>

#define BN_EPS 1e-5f

using f32x4  = __attribute__((ext_vector_type(4))) float;
using bf16x8 = __attribute__((ext_vector_type(8))) short;

// ---- workspace layout (in floats) ----
constexpr int Y2_ELEMS   = 256 * 36 * 436;            // y2 intermediate
constexpr int AFRAG_OFF  = Y2_ELEMS;                  // bf16 A-frags: 3mt x 27ks x 64lane x 8 (ushort)
constexpr int AFRAG_N    = 3 * 27 * 64 * 8;           // 41472 ushorts = 20736 floats
constexpr int CST_OFF    = AFRAG_OFF + AFRAG_N / 2;   // a1,o1,a2,o2,a3,o3 (36 each)
constexpr int WCP_OFF    = CST_OFF + 216;             // Wc padded [o2*36+o][16]
constexpr int F_OFF      = WCP_OFF + 36 * 36 * 16;    // f features 256x288

__device__ __forceinline__ ushort rne_bf16(float f) {
  unsigned u = __float_as_uint(f);
  u += 0x7FFFu + ((u >> 16) & 1u);
  return (ushort)(u >> 16);
}

// ------------------------------------------------------------------
// k0: fold BN consts + pack bf16 A-fragments of Ws + pad Wc
// A-frag layout mirrors mfma_f32_16x16x32_bf16 A operand:
//   lane holds row o = mt*16 + (lane&15), k-slice p = ks*32 + (lane>>4)*8 + i
// ------------------------------------------------------------------
__global__ __launch_bounds__(256) void k0_prep(
    const float* __restrict__ Ws, const float* __restrict__ Wc,
    const float* __restrict__ bt, const float* __restrict__ g1,
    const float* __restrict__ b1, const float* __restrict__ m1,
    const float* __restrict__ v1,
    const float* __restrict__ bs, const float* __restrict__ g2,
    const float* __restrict__ b2, const float* __restrict__ m2,
    const float* __restrict__ v2,
    const float* __restrict__ bc, const float* __restrict__ g3,
    const float* __restrict__ b3, const float* __restrict__ m3,
    const float* __restrict__ v3,
    float* __restrict__ ws) {
  int idx = blockIdx.x * 256 + threadIdx.x;
  if (idx < AFRAG_N) {
    int mt   = idx / 13824;          // 27*512
    int rem  = idx - mt * 13824;
    int ks   = rem / 512;
    int rem2 = rem - ks * 512;
    int lane = rem2 >> 3;
    int i    = rem2 & 7;
    int o    = mt * 16 + (lane & 15);
    int p    = ks * 32 + ((lane >> 4) << 3) + i;
    float val = (o < 36) ? Ws[o * 864 + p] : 0.f;   // pair p = c*24+h
    reinterpret_cast<ushort*>(ws + AFRAG_OFF)[idx] = rne_bf16(val);
  }
  if (idx < 36 * 36 * 16) {
    int row = idx >> 4, k = idx & 15;
    ws[WCP_OFF + idx] = (k < 15) ? Wc[row * 15 + k] : 0.f;
  }
  if (idx < 216) {
    int l = idx / 36, c = idx - l * 36;
    float g, b, m, v, bias;
    if (l < 2)      { g = g1[c]; b = b1[c]; m = m1[c]; v = v1[c]; bias = bt[c]; }
    else if (l < 4) { g = g2[c]; b = b2[c]; m = m2[c]; v = v2[c]; bias = bs[c]; }
    else            { g = g3[c]; b = b3[c]; m = m3[c]; v = v3[c]; bias = bc[c]; }
    float s   = g / sqrtf(v + BN_EPS);
    float off = (bias - m) * s + b;
    ws[CST_OFF + idx] = (l & 1) ? off : s;
  }
}

// ------------------------------------------------------------------
// k1: fused conv1(1x65)+BN/ELU (VALU) + conv2(864-reduce) via bf16 MFMA
// grid (28 t-tiles, 256 samples), 512 threads.
// K split 448/416 (14 + 13 exact K=32 steps); waves 0..2 own one
// 16-o M-tile each, accumulate fp32 across both halves.
// ------------------------------------------------------------------
constexpr int XPITCH = 81;   // x row pitch (+1 pad)
constexpr int WTP    = 68;   // Wt row pitch (float4-aligned)
constexpr int Y1P    = 17;   // y1 row pitch (gcd(17,32)=1: conflict-free)

__device__ __forceinline__ void conv1_pair(
    const float* __restrict__ sx, const float* __restrict__ sWt,
    const float* __restrict__ sc, float* __restrict__ sy1,
    int p, int row) {
  const int c = p / 24;
  const int h = p - c * 24;
  const float* xrow = sx + h * XPITCH;
  const float* wrow = sWt + c * WTP;
  float win[32];
#pragma unroll
  for (int j = 0; j < 32; ++j) win[j] = xrow[j];
  float acc[16];
#pragma unroll
  for (int t = 0; t < 16; ++t) acc[t] = 0.f;
#pragma unroll
  for (int cc = 0; cc < 4; ++cc) {
#pragma unroll
    for (int kq = 0; kq < 4; ++kq) {
      const int kb = cc * 16 + kq * 4;
      float4 w4 = *reinterpret_cast<const float4*>(wrow + kb);
      float wv[4] = {w4.x, w4.y, w4.z, w4.w};
#pragma unroll
      for (int kk = 0; kk < 4; ++kk) {
        const int k = kb + kk;
        const float w = wv[kk];
#pragma unroll
        for (int t = 0; t < 16; ++t)
          acc[t] = fmaf(w, win[(k + t) & 31], acc[t]);
        if (k < 48) win[k & 31] = xrow[k + 32];
      }
    }
  }
  {
    const float w = wrow[64];
#pragma unroll
    for (int t = 0; t < 16; ++t)
      acc[t] = fmaf(w, win[(64 + t) & 31], acc[t]);
  }
  const float a1 = sc[c], o1 = sc[36 + c];
  float* yrow = sy1 + row * Y1P;
#pragma unroll
  for (int t = 0; t < 16; ++t) {
    float v = fmaf(acc[t], a1, o1);
    yrow[t] = v > 0.f ? v : __expf(v) - 1.f;
  }
}

__global__ __launch_bounds__(512) void k1_conv12(
    const float* __restrict__ x, const float* __restrict__ Wt,
    const float* __restrict__ ws_ro, float* __restrict__ y2g) {
  __shared__ float sx[24 * XPITCH];                 // 7776 B
  __shared__ float sWt[36 * WTP];                   // 9792 B
  __shared__ float sy1[448 * Y1P];                  // 30464 B
  __shared__ float sc[144];

  const int tid  = threadIdx.x;
  const int t0   = blockIdx.x * 16;
  const int b    = blockIdx.y;
  const int wid  = tid >> 6;
  const int lane = tid & 63;
  const ushort* afragG = reinterpret_cast<const ushort*>(ws_ro + AFRAG_OFF);

  // ---- stage ----
  for (int i = tid; i < 24 * 80; i += 512) {
    int h = i / 80, col = i - h * 80;
    int gc = t0 + col;
    float v = 0.f;
    if (gc < 500) v = x[b * 24024 + h * 1001 + 501 + gc];
    sx[h * XPITCH + col] = v;
  }
  for (int i = tid; i < 36 * 65; i += 512) {
    int c = i / 65, k = i - c * 65;
    sWt[c * WTP + k] = Wt[i];
  }
  if (tid < 144) sc[tid] = ws_ro[CST_OFF + tid];
  __syncthreads();

  f32x4 acc2 = {0.f, 0.f, 0.f, 0.f};
  const int tcol = lane & 15;
  const int rq   = (lane >> 4) << 3;
  const ushort* abase = afragG + wid * (27 * 512) + lane * 8;

  // ---- conv1 half A: p = 0..447 ----
  if (tid < 448) conv1_pair(sx, sWt, sc, sy1, tid, tid);
  __syncthreads();

  // ---- conv2 half A: K-steps 0..13 (MFMA waves 0..2) ----
  if (wid < 3) {
#pragma unroll
    for (int ks = 0; ks < 14; ++ks) {
      bf16x8 af = *reinterpret_cast<const bf16x8*>(abase + ks * 512);
      const float* yb = sy1 + (ks * 32 + rq) * Y1P + tcol;
      bf16x8 bfv;
#pragma unroll
      for (int i = 0; i < 8; ++i) bfv[i] = (short)rne_bf16(yb[i * Y1P]);
      acc2 = __builtin_amdgcn_mfma_f32_16x16x32_bf16(af, bfv, acc2, 0, 0, 0);
    }
  }
  __syncthreads();

  // ---- conv1 half B: p = 448..863 -> rows 0..415 ----
  if (tid < 416) conv1_pair(sx, sWt, sc, sy1, 448 + tid, tid);
  __syncthreads();

  // ---- conv2 half B: K-steps 14..26 ----
  if (wid < 3) {
#pragma unroll
    for (int ks = 14; ks < 27; ++ks) {
      bf16x8 af = *reinterpret_cast<const bf16x8*>(abase + ks * 512);
      const float* yb = sy1 + ((ks - 14) * 32 + rq) * Y1P + tcol;
      bf16x8 bfv;
#pragma unroll
      for (int i = 0; i < 8; ++i) bfv[i] = (short)rne_bf16(yb[i * Y1P]);
      acc2 = __builtin_amdgcn_mfma_f32_16x16x32_bf16(af, bfv, acc2, 0, 0, 0);
    }

    // ---- epilogue: BN2 + ELU + store (C/D: col=lane&15, row=(lane>>4)*4+r) ----
    const int gt    = t0 + tcol;
    const int orow0 = wid * 16 + ((lane >> 4) << 2);
#pragma unroll
    for (int r = 0; r < 4; ++r) {
      const int o = orow0 + r;
      if (o < 36 && gt < 436) {
        float v = fmaf(acc2[r], sc[72 + o], sc[108 + o]);
        v = v > 0.f ? v : __expf(v) - 1.f;
        y2g[(b * 36 + o) * 436 + gt] = v;
      }
    }
  }
}

// ------------------------------------------------------------------
// k2a: pool3 + conv3(1x15) + BN/ELU + pool15 -> f (256x288)
// grid (256 samples, 4 segments), 320 threads
// ------------------------------------------------------------------
__global__ __launch_bounds__(320) void k2a_feat(
    const float* __restrict__ y2g, const float* __restrict__ ws_ro,
    float* __restrict__ fws) {
  __shared__ float sy2[36 * 136];
  __shared__ float sp[36 * 48 + 8];
  __shared__ float sy3[36 * 32];
  const int tid = threadIdx.x;
  const int b   = blockIdx.x;
  const int seg = blockIdx.y;
  const int y2base = seg * 90;

  for (int i = tid; i < 36 * 135; i += 320) {
    int o = i / 135, col = i - o * 135;
    sy2[o * 136 + col] = y2g[(b * 36 + o) * 436 + y2base + col];
  }
  __syncthreads();

  for (int i = tid; i < 36 * 45; i += 320) {
    int o = i / 45, u = i - o * 45;
    const float* rp = sy2 + o * 136 + u * 3;
    sp[o * 48 + u] = (rp[0] + rp[1] + rp[2]) * (1.f / 3.f);
  }
  for (int i = tid; i < 36 * 3; i += 320) {
    int o = i / 3;
    sp[o * 48 + 45 + (i % 3)] = 0.f;
  }
  __syncthreads();

  // conv3: 288 units = 36 o2 x 8 t3-blocks(4)
  if (tid < 288) {
    const int o2 = tid >> 3, tb = tid & 7;
    float accv[4] = {0.f, 0.f, 0.f, 0.f};
    const float* wbase = ws_ro + WCP_OFF + (o2 * 36) * 16;
    for (int o = 0; o < 36; ++o) {
      const float* pr = sp + o * 48 + tb * 4;
      float4 p0 = reinterpret_cast<const float4*>(pr)[0];
      float4 p1 = reinterpret_cast<const float4*>(pr)[1];
      float4 p2 = reinterpret_cast<const float4*>(pr)[2];
      float4 p3 = reinterpret_cast<const float4*>(pr)[3];
      float4 p4 = reinterpret_cast<const float4*>(pr)[4];
      float win[20] = {p0.x, p0.y, p0.z, p0.w, p1.x, p1.y, p1.z, p1.w,
                       p2.x, p2.y, p2.z, p2.w, p3.x, p3.y, p3.z, p3.w,
                       p4.x, p4.y, p4.z, p4.w};
      const float4* wr = reinterpret_cast<const float4*>(wbase + o * 16);
      float4 w0 = wr[0], w1 = wr[1], w2 = wr[2], w3 = wr[3];
      float w[15] = {w0.x, w0.y, w0.z, w0.w, w1.x, w1.y, w1.z, w1.w,
                     w2.x, w2.y, w2.z, w2.w, w3.x, w3.y, w3.z};
#pragma unroll
      for (int k = 0; k < 15; ++k)
#pragma unroll
        for (int t = 0; t < 4; ++t)
          accv[t] = fmaf(w[k], win[k + t], accv[t]);
    }
    const float a3 = ws_ro[CST_OFF + 144 + o2];
    const float o3c = ws_ro[CST_OFF + 180 + o2];
#pragma unroll
    for (int t = 0; t < 4; ++t) {
      const int t3 = tb * 4 + t;
      if (t3 < 30) {
        float v = fmaf(accv[t], a3, o3c);
        sy3[o2 * 32 + t3] = v > 0.f ? v : __expf(v) - 1.f;
      }
    }
  }
  __syncthreads();

  // pool15 -> f (72 outputs this segment)
  if (tid < 72) {
    const int o2 = tid >> 1, jl = tid & 1;
    const float* rp = sy3 + o2 * 32 + jl * 15;
    float s = 0.f;
#pragma unroll
    for (int k = 0; k < 15; ++k) s += rp[k];
    fws[b * 288 + o2 * 8 + seg * 2 + jl] = s * (1.f / 15.f);
  }
}

// ------------------------------------------------------------------
// k2b: FC 288x288 + residual + /501
// ------------------------------------------------------------------
__global__ __launch_bounds__(320) void k2b_fc(
    const float* __restrict__ fws, const float* __restrict__ Wf,
    const float* __restrict__ bfv, float* __restrict__ out) {
  __shared__ float sf[288];
  const int tid = threadIdx.x, b = blockIdx.x;
  if (tid < 288) sf[tid] = fws[b * 288 + tid];
  __syncthreads();
  if (tid < 288) {
    const int n = tid;
    float acc = bfv[n] + sf[n];
#pragma unroll 4
    for (int m = 0; m < 288; ++m) acc = fmaf(sf[m], Wf[m * 288 + n], acc);
    out[b * 288 + n] = acc * (1.f / 501.f);
  }
}

// ------------------------------------------------------------------
extern "C" void kernel_launch(void* const* d_in, const int* in_sizes, int n_in,
                              void* d_out, int out_size, void* d_ws, size_t ws_size,
                              hipStream_t stream) {
  const float* x  = (const float*)d_in[0];
  const float* Wt = (const float*)d_in[1];
  const float* bt = (const float*)d_in[2];
  const float* g1 = (const float*)d_in[3];
  const float* b1 = (const float*)d_in[4];
  const float* m1 = (const float*)d_in[5];
  const float* v1 = (const float*)d_in[6];
  const float* Ws = (const float*)d_in[7];
  const float* bs = (const float*)d_in[8];
  const float* g2 = (const float*)d_in[9];
  const float* b2 = (const float*)d_in[10];
  const float* m2 = (const float*)d_in[11];
  const float* v2 = (const float*)d_in[12];
  const float* Wc = (const float*)d_in[13];
  const float* bc = (const float*)d_in[14];
  const float* g3 = (const float*)d_in[15];
  const float* b3 = (const float*)d_in[16];
  const float* m3 = (const float*)d_in[17];
  const float* v3 = (const float*)d_in[18];
  const float* Wf = (const float*)d_in[19];
  const float* bf = (const float*)d_in[20];

  float* ws  = (float*)d_ws;
  float* out = (float*)d_out;

  k0_prep<<<dim3(162), dim3(256), 0, stream>>>(Ws, Wc, bt, g1, b1, m1, v1,
                                               bs, g2, b2, m2, v2,
                                               bc, g3, b3, m3, v3, ws);
  k1_conv12<<<dim3(28, 256), dim3(512), 0, stream>>>(x, Wt, ws, ws);
  k2a_feat<<<dim3(256, 4), dim3(320), 0, stream>>>(ws, ws, ws + F_OFF);
  k2b_fc<<<dim3(256), dim3(320), 0, stream>>>(ws + F_OFF, Wf, bf, out);
}

// Round 13
// 288.853 us; speedup vs baseline: 4.0343x; 1.3303x over previous
//
#include <hip/hip_runtime.h>
#include <math.h>

#define BN_EPS 1e-5f

using f32x4  = __attribute__((ext_vector_type(4))) float;
using bf16x8 = __attribute__((ext_vector_type(8))) short;
using bf16x4 = __attribute__((ext_vector_type(4))) short;

// ---- workspace layout (in floats) ----
constexpr int Y2_ELEMS   = 256 * 36 * 436;            // y2 intermediate
constexpr int AFRAG_N    = 3 * 27 * 64 * 8;           // conv2 A-frags (ushorts)
constexpr int AFRAG_OFF  = Y2_ELEMS;
constexpr int AFRAG1_N   = 3 * 2 * 64 * 8;            // conv1 A-frags (ushorts)
constexpr int AFRAG1_OFF = AFRAG_OFF + AFRAG_N / 2;
constexpr int CST_OFF    = AFRAG1_OFF + AFRAG1_N / 2; // a1,o1,a2,o2,a3,o3 (36 each)
constexpr int WCP_OFF    = CST_OFF + 216;             // Wc padded [o2*36+o][16]
constexpr int F_OFF      = WCP_OFF + 36 * 36 * 16;    // f features 256x288

__device__ __forceinline__ ushort rne_bf16(float f) {
  unsigned u = __float_as_uint(f);
  u += 0x7FFFu + ((u >> 16) & 1u);
  return (ushort)(u >> 16);
}
__device__ __forceinline__ float bf_to_f(ushort u) {
  return __uint_as_float(((unsigned)u) << 16);
}

// ------------------------------------------------------------------
// k0: fold BN consts + pack bf16 A-frags (conv2 Ws, conv1 Wt) + pad Wc
// A-frag layout (mfma_f32_16x16x32_bf16 A): lane holds row o=(lane&15),
// k = (lane>>4)*8 + i within the 32-slice.
// ------------------------------------------------------------------
__global__ __launch_bounds__(256) void k0_prep(
    const float* __restrict__ Ws, const float* __restrict__ Wc,
    const float* __restrict__ Wt,
    const float* __restrict__ bt, const float* __restrict__ g1,
    const float* __restrict__ b1, const float* __restrict__ m1,
    const float* __restrict__ v1,
    const float* __restrict__ bs, const float* __restrict__ g2,
    const float* __restrict__ b2, const float* __restrict__ m2,
    const float* __restrict__ v2,
    const float* __restrict__ bc, const float* __restrict__ g3,
    const float* __restrict__ b3, const float* __restrict__ m3,
    const float* __restrict__ v3,
    float* __restrict__ ws) {
  int idx = blockIdx.x * 256 + threadIdx.x;
  if (idx < AFRAG_N) {            // conv2: Ws[o*864 + p], 3 mt x 27 ks
    int mt   = idx / 13824;       // 27*512
    int rem  = idx - mt * 13824;
    int ks   = rem / 512;
    int rem2 = rem - ks * 512;
    int lane = rem2 >> 3;
    int i    = rem2 & 7;
    int o    = mt * 16 + (lane & 15);
    int p    = ks * 32 + ((lane >> 4) << 3) + i;
    float val = (o < 36) ? Ws[o * 864 + p] : 0.f;
    reinterpret_cast<ushort*>(ws + AFRAG_OFF)[idx] = rne_bf16(val);
  }
  if (idx < AFRAG1_N) {           // conv1: Wt[c*65 + k], 3 mt x 2 ks2 (k<64)
    int mt   = idx / 1024;        // 2*512
    int rem  = idx - mt * 1024;
    int ks2  = rem >> 9;
    int r2   = rem & 511;
    int lane = r2 >> 3;
    int i    = r2 & 7;
    int c    = mt * 16 + (lane & 15);
    int k    = ks2 * 32 + ((lane >> 4) << 3) + i;
    float val = (c < 36) ? Wt[c * 65 + k] : 0.f;
    reinterpret_cast<ushort*>(ws + AFRAG1_OFF)[idx] = rne_bf16(val);
  }
  if (idx < 36 * 36 * 16) {
    int row = idx >> 4, k = idx & 15;
    ws[WCP_OFF + idx] = (k < 15) ? Wc[row * 15 + k] : 0.f;
  }
  if (idx < 216) {
    int l = idx / 36, c = idx - l * 36;
    float g, b, m, v, bias;
    if (l < 2)      { g = g1[c]; b = b1[c]; m = m1[c]; v = v1[c]; bias = bt[c]; }
    else if (l < 4) { g = g2[c]; b = b2[c]; m = m2[c]; v = v2[c]; bias = bs[c]; }
    else            { g = g3[c]; b = b3[c]; m = m3[c]; v = v3[c]; bias = bc[c]; }
    float s   = g / sqrtf(v + BN_EPS);
    float off = (bias - m) * s + b;
    ws[CST_OFF + idx] = (l & 1) ? off : s;
  }
}

// ------------------------------------------------------------------
// k1: conv1 via MFMA (x split hi+lo bf16, W bf16, k=64 tap fp32)
//     + conv2 via MFMA (y1 bf16 in LDS [t][p] skewed layout)
// grid (28 t-tiles, 256 samples), 512 threads, 2 barriers.
// ------------------------------------------------------------------
constexpr int XP = 80;    // sxhi/sxlo pitch (shorts)

__device__ __forceinline__ int yrow_off(int t) {
  // skewed row offset (shorts): 16 distinct banks across t for scatter writes,
  // keeps 8B alignment for ds_read_b64 (t*1744 + (t>>3)*8 bytes).
  return t * 872 + ((t >> 3) << 2);
}

__global__ __launch_bounds__(512) void k1_conv12(
    const float* __restrict__ x, const float* __restrict__ Wt,
    const float* __restrict__ ws_ro, float* __restrict__ y2g) {
  __shared__ ushort sxhi[24 * XP];                       // 3840 B
  __shared__ ushort sxlo[24 * XP];                       // 3840 B
  __shared__ alignas(16) ushort sy1[16 * 872 + 4];       // 27912 B
  __shared__ float sc[180];

  const int tid  = threadIdx.x;
  const int t0   = blockIdx.x * 16;
  const int b    = blockIdx.y;
  const int wid  = tid >> 6;
  const int lane = tid & 63;
  const int tcol = lane & 15;
  const int q    = lane >> 4;
  const int rq   = q << 3;

  // ---- stage: x -> (hi, lo) bf16 pair; consts; tap weights ----
  for (int i = tid; i < 24 * 80; i += 512) {
    int h = i / 80, col = i - h * 80;
    int gc = t0 + col;
    float v = (gc < 500) ? x[b * 24024 + h * 1001 + 501 + gc] : 0.f;
    ushort hi = rne_bf16(v);
    ushort lo = rne_bf16(v - bf_to_f(hi));
    sxhi[h * XP + col] = hi;
    sxlo[h * XP + col] = lo;
  }
  if (tid < 144) sc[tid] = ws_ro[CST_OFF + tid];
  if (tid >= 144 && tid < 180) sc[tid] = Wt[(tid - 144) * 65 + 64];

  // conv1 A-frags (bf16 Wt) global -> VGPR (L2-broadcast across blocks)
  const ushort* a1G = reinterpret_cast<const ushort*>(ws_ro + AFRAG1_OFF) + lane * 8;
  bf16x8 a1f00 = *reinterpret_cast<const bf16x8*>(a1G + 0 * 512);
  bf16x8 a1f01 = *reinterpret_cast<const bf16x8*>(a1G + 1 * 512);
  bf16x8 a1f10 = *reinterpret_cast<const bf16x8*>(a1G + 2 * 512);
  bf16x8 a1f11 = *reinterpret_cast<const bf16x8*>(a1G + 3 * 512);
  bf16x8 a1f20 = *reinterpret_cast<const bf16x8*>(a1G + 4 * 512);
  bf16x8 a1f21 = *reinterpret_cast<const bf16x8*>(a1G + 5 * 512);
  __syncthreads();

  // ---- conv1: 3 h-rows per wave, all-MFMA + fp32 tap ----
  const int tq = yrow_off(tcol);
#pragma unroll 1
  for (int j = 0; j < 3; ++j) {
    const int h = wid * 3 + j;
    const ushort* xh = sxhi + h * XP + tcol;
    const ushort* xl = sxlo + h * XP + tcol;
    f32x4 c0 = {0.f, 0.f, 0.f, 0.f};
    f32x4 c1 = {0.f, 0.f, 0.f, 0.f};
    f32x4 c2 = {0.f, 0.f, 0.f, 0.f};
    // ks2 = 0 (k 0..31)
    {
      bf16x8 bh, bl;
#pragma unroll
      for (int i = 0; i < 8; ++i) {
        bh[i] = (short)xh[rq + i];
        bl[i] = (short)xl[rq + i];
      }
      c0 = __builtin_amdgcn_mfma_f32_16x16x32_bf16(a1f00, bh, c0, 0, 0, 0);
      c1 = __builtin_amdgcn_mfma_f32_16x16x32_bf16(a1f10, bh, c1, 0, 0, 0);
      c2 = __builtin_amdgcn_mfma_f32_16x16x32_bf16(a1f20, bh, c2, 0, 0, 0);
      c0 = __builtin_amdgcn_mfma_f32_16x16x32_bf16(a1f00, bl, c0, 0, 0, 0);
      c1 = __builtin_amdgcn_mfma_f32_16x16x32_bf16(a1f10, bl, c1, 0, 0, 0);
      c2 = __builtin_amdgcn_mfma_f32_16x16x32_bf16(a1f20, bl, c2, 0, 0, 0);
    }
    // ks2 = 1 (k 32..63)
    {
      bf16x8 bh, bl;
#pragma unroll
      for (int i = 0; i < 8; ++i) {
        bh[i] = (short)xh[32 + rq + i];
        bl[i] = (short)xl[32 + rq + i];
      }
      c0 = __builtin_amdgcn_mfma_f32_16x16x32_bf16(a1f01, bh, c0, 0, 0, 0);
      c1 = __builtin_amdgcn_mfma_f32_16x16x32_bf16(a1f11, bh, c1, 0, 0, 0);
      c2 = __builtin_amdgcn_mfma_f32_16x16x32_bf16(a1f21, bh, c2, 0, 0, 0);
      c0 = __builtin_amdgcn_mfma_f32_16x16x32_bf16(a1f01, bl, c0, 0, 0, 0);
      c1 = __builtin_amdgcn_mfma_f32_16x16x32_bf16(a1f11, bl, c1, 0, 0, 0);
      c2 = __builtin_amdgcn_mfma_f32_16x16x32_bf16(a1f21, bl, c2, 0, 0, 0);
    }
    // tap k = 64 (exact fp32)
    {
      const float xv = bf_to_f(xh[64]) + bf_to_f(xl[64]);
#pragma unroll
      for (int r = 0; r < 4; ++r) {
        c0[r] = fmaf(sc[144 + (q * 4 + r)], xv, c0[r]);
        c1[r] = fmaf(sc[144 + 16 + (q * 4 + r)], xv, c1[r]);
      }
      if (q == 0) {
#pragma unroll
        for (int r = 0; r < 4; ++r)
          c2[r] = fmaf(sc[144 + 32 + r], xv, c2[r]);
      }
    }
    // epilogue: BN1 + ELU + bf16 store to sy1[t][p=c*24+h]
#pragma unroll
    for (int r = 0; r < 4; ++r) {
      {
        const int c = q * 4 + r;
        float v = fmaf(c0[r], sc[c], sc[36 + c]);
        v = v > 0.f ? v : __expf(v) - 1.f;
        sy1[tq + c * 24 + h] = rne_bf16(v);
      }
      {
        const int c = 16 + q * 4 + r;
        float v = fmaf(c1[r], sc[c], sc[36 + c]);
        v = v > 0.f ? v : __expf(v) - 1.f;
        sy1[tq + c * 24 + h] = rne_bf16(v);
      }
    }
    if (q == 0) {
#pragma unroll
      for (int r = 0; r < 4; ++r) {
        const int c = 32 + r;
        float v = fmaf(c2[r], sc[c], sc[36 + c]);
        v = v > 0.f ? v : __expf(v) - 1.f;
        sy1[tq + c * 24 + h] = rne_bf16(v);
      }
    }
  }
  __syncthreads();

  // ---- conv2: waves 0..2 (mt = wid), 27 K-steps over full p-range ----
  if (wid < 3) {
    const ushort* abase =
        reinterpret_cast<const ushort*>(ws_ro + AFRAG_OFF) + wid * (27 * 512) + lane * 8;
    f32x4 a2 = {0.f, 0.f, 0.f, 0.f};
    for (int ks = 0; ks < 27; ++ks) {
      bf16x8 af = *reinterpret_cast<const bf16x8*>(abase + ks * 512);
      bf16x4 b0 = *reinterpret_cast<const bf16x4*>(sy1 + tq + ks * 32 + rq);
      bf16x4 b1 = *reinterpret_cast<const bf16x4*>(sy1 + tq + ks * 32 + rq + 4);
      bf16x8 bf;
#pragma unroll
      for (int i = 0; i < 4; ++i) { bf[i] = b0[i]; bf[4 + i] = b1[i]; }
      a2 = __builtin_amdgcn_mfma_f32_16x16x32_bf16(af, bf, a2, 0, 0, 0);
    }
    // epilogue: BN2 + ELU + store (C/D: col=lane&15, row=(lane>>4)*4+r)
    const int gt    = t0 + tcol;
    const int orow0 = wid * 16 + (q << 2);
#pragma unroll
    for (int r = 0; r < 4; ++r) {
      const int o = orow0 + r;
      if (o < 36 && gt < 436) {
        float v = fmaf(a2[r], sc[72 + o], sc[108 + o]);
        v = v > 0.f ? v : __expf(v) - 1.f;
        y2g[(b * 36 + o) * 436 + gt] = v;
      }
    }
  }
}

// ------------------------------------------------------------------
// k2a: pool3 + conv3(1x15) + BN/ELU + pool15 -> f (256x288)
// grid (256 samples, 4 segments), 320 threads
// ------------------------------------------------------------------
__global__ __launch_bounds__(320) void k2a_feat(
    const float* __restrict__ y2g, const float* __restrict__ ws_ro,
    float* __restrict__ fws) {
  __shared__ float sy2[36 * 136];
  __shared__ float sp[36 * 48 + 8];
  __shared__ float sy3[36 * 32];
  const int tid = threadIdx.x;
  const int b   = blockIdx.x;
  const int seg = blockIdx.y;
  const int y2base = seg * 90;

  for (int i = tid; i < 36 * 135; i += 320) {
    int o = i / 135, col = i - o * 135;
    sy2[o * 136 + col] = y2g[(b * 36 + o) * 436 + y2base + col];
  }
  __syncthreads();

  for (int i = tid; i < 36 * 45; i += 320) {
    int o = i / 45, u = i - o * 45;
    const float* rp = sy2 + o * 136 + u * 3;
    sp[o * 48 + u] = (rp[0] + rp[1] + rp[2]) * (1.f / 3.f);
  }
  for (int i = tid; i < 36 * 3; i += 320) {
    int o = i / 3;
    sp[o * 48 + 45 + (i % 3)] = 0.f;
  }
  __syncthreads();

  // conv3: 288 units = 36 o2 x 8 t3-blocks(4)
  if (tid < 288) {
    const int o2 = tid >> 3, tb = tid & 7;
    float accv[4] = {0.f, 0.f, 0.f, 0.f};
    const float* wbase = ws_ro + WCP_OFF + (o2 * 36) * 16;
    for (int o = 0; o < 36; ++o) {
      const float* pr = sp + o * 48 + tb * 4;
      float4 p0 = reinterpret_cast<const float4*>(pr)[0];
      float4 p1 = reinterpret_cast<const float4*>(pr)[1];
      float4 p2 = reinterpret_cast<const float4*>(pr)[2];
      float4 p3 = reinterpret_cast<const float4*>(pr)[3];
      float4 p4 = reinterpret_cast<const float4*>(pr)[4];
      float win[20] = {p0.x, p0.y, p0.z, p0.w, p1.x, p1.y, p1.z, p1.w,
                       p2.x, p2.y, p2.z, p2.w, p3.x, p3.y, p3.z, p3.w,
                       p4.x, p4.y, p4.z, p4.w};
      const float4* wr = reinterpret_cast<const float4*>(wbase + o * 16);
      float4 w0 = wr[0], w1 = wr[1], w2 = wr[2], w3 = wr[3];
      float w[15] = {w0.x, w0.y, w0.z, w0.w, w1.x, w1.y, w1.z, w1.w,
                     w2.x, w2.y, w2.z, w2.w, w3.x, w3.y, w3.z};
#pragma unroll
      for (int k = 0; k < 15; ++k)
#pragma unroll
        for (int t = 0; t < 4; ++t)
          accv[t] = fmaf(w[k], win[k + t], accv[t]);
    }
    const float a3 = ws_ro[CST_OFF + 144 + o2];
    const float o3c = ws_ro[CST_OFF + 180 + o2];
#pragma unroll
    for (int t = 0; t < 4; ++t) {
      const int t3 = tb * 4 + t;
      if (t3 < 30) {
        float v = fmaf(accv[t], a3, o3c);
        sy3[o2 * 32 + t3] = v > 0.f ? v : __expf(v) - 1.f;
      }
    }
  }
  __syncthreads();

  // pool15 -> f (72 outputs this segment)
  if (tid < 72) {
    const int o2 = tid >> 1, jl = tid & 1;
    const float* rp = sy3 + o2 * 32 + jl * 15;
    float s = 0.f;
#pragma unroll
    for (int k = 0; k < 15; ++k) s += rp[k];
    fws[b * 288 + o2 * 8 + seg * 2 + jl] = s * (1.f / 15.f);
  }
}

// ------------------------------------------------------------------
// k2b: FC 288x288 + residual + /501
// ------------------------------------------------------------------
__global__ __launch_bounds__(320) void k2b_fc(
    const float* __restrict__ fws, const float* __restrict__ Wf,
    const float* __restrict__ bfv, float* __restrict__ out) {
  __shared__ float sf[288];
  const int tid = threadIdx.x, b = blockIdx.x;
  if (tid < 288) sf[tid] = fws[b * 288 + tid];
  __syncthreads();
  if (tid < 288) {
    const int n = tid;
    float acc = bfv[n] + sf[n];
#pragma unroll 4
    for (int m = 0; m < 288; ++m) acc = fmaf(sf[m], Wf[m * 288 + n], acc);
    out[b * 288 + n] = acc * (1.f / 501.f);
  }
}

// ------------------------------------------------------------------
extern "C" void kernel_launch(void* const* d_in, const int* in_sizes, int n_in,
                              void* d_out, int out_size, void* d_ws, size_t ws_size,
                              hipStream_t stream) {
  const float* x  = (const float*)d_in[0];
  const float* Wt = (const float*)d_in[1];
  const float* bt = (const float*)d_in[2];
  const float* g1 = (const float*)d_in[3];
  const float* b1 = (const float*)d_in[4];
  const float* m1 = (const float*)d_in[5];
  const float* v1 = (const float*)d_in[6];
  const float* Ws = (const float*)d_in[7];
  const float* bs = (const float*)d_in[8];
  const float* g2 = (const float*)d_in[9];
  const float* b2 = (const float*)d_in[10];
  const float* m2 = (const float*)d_in[11];
  const float* v2 = (const float*)d_in[12];
  const float* Wc = (const float*)d_in[13];
  const float* bc = (const float*)d_in[14];
  const float* g3 = (const float*)d_in[15];
  const float* b3 = (const float*)d_in[16];
  const float* m3 = (const float*)d_in[17];
  const float* v3 = (const float*)d_in[18];
  const float* Wf = (const float*)d_in[19];
  const float* bf = (const float*)d_in[20];

  float* ws  = (float*)d_ws;
  float* out = (float*)d_out;

  k0_prep<<<dim3(162), dim3(256), 0, stream>>>(Ws, Wc, Wt, bt, g1, b1, m1, v1,
                                               bs, g2, b2, m2, v2,
                                               bc, g3, b3, m3, v3, ws);
  k1_conv12<<<dim3(28, 256), dim3(512), 0, stream>>>(x, Wt, ws, ws);
  k2a_feat<<<dim3(256, 4), dim3(320), 0, stream>>>(ws, ws, ws + F_OFF);
  k2b_fc<<<dim3(256), dim3(320), 0, stream>>>(ws + F_OFF, Wf, bf, out);
}